// Round 8
// baseline (237.375 us; speedup 1.0000x reference)
//
#include <hip/hip_runtime.h>
#include <hip/hip_bf16.h>

// Caterpillar: N=2 T=4096 D=1024 H=8 E=4 L=32 DK=DV=64
// R8: 8-wave attn (parallel e-halves + flash-merge via LDS), prep kernels merged.
//     proj/out GEMMs (R7 ring-3 128^2), gate, scan unchanged from passing R7.

using f4 = float4;
typedef __attribute__((ext_vector_type(8))) short short8;   // 8 bf16
typedef __attribute__((ext_vector_type(4))) float floatx4;  // 4 fp32 acc

__device__ __forceinline__ ushort f2bf(float x) {
  unsigned u = __float_as_uint(x);
  u += 0x7fffu + ((u >> 16) & 1u);   // RNE
  return (ushort)(u >> 16);
}
__device__ __forceinline__ unsigned pk2(float lo, float hi) {
  return (unsigned)f2bf(lo) | ((unsigned)f2bf(hi) << 16);
}

__device__ __forceinline__ void gll16(const void* g, void* l) {
  __builtin_amdgcn_global_load_lds((const __attribute__((address_space(1))) void*)g,
                                   (__attribute__((address_space(3))) void*)l, 16, 0, 0);
}

// ---------------- fused prep: X->bf16, weights->wAll, wO transpose ----------------
__global__ __launch_bounds__(256)
void prep_kernel(const float* __restrict__ X,
                 const float* __restrict__ wK, const float* __restrict__ wV,
                 const float* __restrict__ wQ, const float* __restrict__ wG,
                 const float* __restrict__ wO,
                 ushort* __restrict__ Xbf, ushort* __restrict__ wAll,
                 ushort* __restrict__ wObf)
{
  const int b = blockIdx.x;
  if (b < 2048) {
    // X: 2097152 float4 -> bf16x4, 4 per thread
    int i0 = b * 256 + threadIdx.x;
#pragma unroll
    for (int k = 0; k < 4; k++) {
      int idx = i0 + k * 524288;
      f4 v = ((const f4*)X)[idx];
      ushort4 o; o.x = f2bf(v.x); o.y = f2bf(v.y); o.z = f2bf(v.z); o.w = f2bf(v.w);
      ((ushort4*)Xbf)[idx] = o;
    }
  } else if (b < 3712) {
    // wAll rows: [0,512)=wK, [512,1024)=wV, [1024,1536)=wQ, [1536,1568)=wG, rest 0
    int i4 = (b - 2048) * 256 + threadIdx.x;   // 0..425983
    int idx = i4 * 4;
    int row = idx >> 10;
    f4 v = make_float4(0.f, 0.f, 0.f, 0.f);
    if (row < 512)       v = *(const f4*)&wK[idx];
    else if (row < 1024) v = *(const f4*)&wV[idx - 524288];
    else if (row < 1536) v = *(const f4*)&wQ[idx - 1048576];
    else if (row < 1568) v = *(const f4*)&wG[idx - 1572864];
    ushort4 o; o.x = f2bf(v.x); o.y = f2bf(v.y); o.z = f2bf(v.z); o.w = f2bf(v.w);
    *(ushort4*)&wAll[idx] = o;
  } else {
    // wObf[n][k] = wO[k][n]
    int i = (b - 3712) * 256 + threadIdx.x;    // 0..524287
    int n = i >> 9, k = i & 511;
    wObf[i] = f2bf(wO[(size_t)k * 1024 + n]);
  }
}

// ---------------- 128^2 GEMM step (ring-3, swizzled) ----------------
#define GSTEP(LDA_, WAITS, STAGE_, KT) do {                                       \
  asm volatile("s_waitcnt vmcnt(" WAITS ")" ::: "memory");                        \
  __builtin_amdgcn_s_barrier();                                                   \
  if (STAGE_) {                                                                   \
    const ushort* ga = gA + (size_t)((KT) + 2) * 32;                              \
    const ushort* gb = gB + (size_t)((KT) + 2) * 32;                              \
    ushort* la = As + ss * 4096 + tid * 8;                                        \
    ushort* lb = Bs + ss * 4096 + tid * 8;                                        \
    gll16(ga, la); gll16(ga + 64 * (LDA_), la + 2048);                            \
    gll16(gb, lb); gll16(gb + 64 * (LDA_), lb + 2048);                            \
  }                                                                               \
  {                                                                               \
    const ushort* Afp = As + cs * 4096 + (wm + l15) * 32 + koff;                  \
    const ushort* Bfp = Bs + cs * 4096 + (wn + l15) * 32 + koff;                  \
    short8 bf_[4];                                                                \
    _Pragma("unroll")                                                             \
    for (int ni = 0; ni < 4; ni++) bf_[ni] = *(const short8*)(Bfp + ni * 512);    \
    __builtin_amdgcn_s_setprio(1);                                                \
    _Pragma("unroll")                                                             \
    for (int mi = 0; mi < 4; mi++) {                                              \
      short8 af_ = *(const short8*)(Afp + mi * 512);                              \
      _Pragma("unroll")                                                           \
      for (int ni = 0; ni < 4; ni++)                                              \
        acc[mi][ni] = __builtin_amdgcn_mfma_f32_16x16x32_bf16(                    \
            af_, bf_[ni], acc[mi][ni], 0, 0, 0);                                  \
    }                                                                             \
    __builtin_amdgcn_s_setprio(0);                                                \
    cs = (cs == 2) ? 0 : cs + 1;                                                  \
    ss = (ss == 2) ? 0 : ss + 1;                                                  \
  }                                                                               \
} while (0)

// ---------------- projection GEMM ----------------
__global__ __launch_bounds__(256, 3)
void proj_gemm_128s(const ushort* __restrict__ Xbf, const ushort* __restrict__ wAll,
                    float* __restrict__ Kp, float* __restrict__ Vp,
                    ushort* __restrict__ Qbf, float* __restrict__ Glin)
{
  __shared__ ushort As[3 * 4096];
  __shared__ ushort Bs[3 * 4096];

  const int tid = threadIdx.x;
  const int bid = blockIdx.x;               // 0..831
  const int xcd = bid & 7, slot = bid >> 3;
  const int ct = slot % 13;
  const int my = xcd * 8 + slot / 13;
  const int m0 = my * 128, n0 = ct * 128;

  const int lane = tid & 63, w = tid >> 6;
  const int wm = (w >> 1) * 64, wn = (w & 1) * 64;
  const int l15 = lane & 15, lg = lane >> 4;
  const int fl = (l15 & 3) ^ ((l15 >> 2) & 3);
  const int koff = ((lg ^ fl) & 3) * 8;

  const int srow = tid >> 2;
  const int schunk = (tid & 3) ^ ((srow & 3) ^ ((srow >> 2) & 3));
  const ushort* gA = Xbf  + (size_t)(m0 + srow) * 1024 + schunk * 8;
  const ushort* gB = wAll + (size_t)(n0 + srow) * 1024 + schunk * 8;

  floatx4 acc[4][4];
#pragma unroll
  for (int mi = 0; mi < 4; mi++)
#pragma unroll
    for (int ni = 0; ni < 4; ni++) acc[mi][ni] = (floatx4){0.f, 0.f, 0.f, 0.f};

#pragma unroll
  for (int t_ = 0; t_ < 2; t_++) {
    const ushort* ga = gA + t_ * 32;
    const ushort* gb = gB + t_ * 32;
    ushort* la = As + t_ * 4096 + tid * 8;
    ushort* lb = Bs + t_ * 4096 + tid * 8;
    gll16(ga, la); gll16(ga + 65536, la + 2048);
    gll16(gb, lb); gll16(gb + 65536, lb + 2048);
  }
  int cs = 0, ss = 2;

#pragma unroll 1
  for (int kt = 0; kt < 31; ++kt) GSTEP(1024, "4", kt <= 29, kt);
  GSTEP(1024, "0", false, 31);

#pragma unroll
  for (int mi = 0; mi < 4; mi++) {
    const int rm = m0 + wm + mi * 16 + lg * 4;
#pragma unroll
    for (int ni = 0; ni < 4; ni++) {
      const int Cg = n0 + wn + ni * 16 + l15;
#pragma unroll
      for (int j = 0; j < 4; j++) {
        const float v = acc[mi][ni][j];
        if (Cg < 512)        Kp [(size_t)(rm + j) * 512 + Cg] = v;
        else if (Cg < 1024)  Vp [(size_t)(rm + j) * 512 + Cg - 512] = v;
        else if (Cg < 1536)  Qbf[(size_t)(rm + j) * 512 + Cg - 1024] = f2bf(v * 0.125f);
        else if (Cg < 1568)  Glin[(size_t)(rm + j) * 32 + Cg - 1536] = v;
      }
    }
  }
}

// ---------------- output GEMM ----------------
__global__ __launch_bounds__(256, 3)
void out_gemm_128s(const ushort* __restrict__ Ybf, const ushort* __restrict__ wObf,
                   float* __restrict__ out)
{
  __shared__ ushort As[3 * 4096];
  __shared__ ushort Bs[3 * 4096];

  const int tid = threadIdx.x;
  const int bid = blockIdx.x;               // 0..511
  const int xcd = bid & 7, slot = bid >> 3;
  const int ct = slot & 7;
  const int my = xcd * 8 + (slot >> 3);
  const int m0 = my * 128, n0 = ct * 128;

  const int lane = tid & 63, w = tid >> 6;
  const int wm = (w >> 1) * 64, wn = (w & 1) * 64;
  const int l15 = lane & 15, lg = lane >> 4;
  const int fl = (l15 & 3) ^ ((l15 >> 2) & 3);
  const int koff = ((lg ^ fl) & 3) * 8;

  const int srow = tid >> 2;
  const int schunk = (tid & 3) ^ ((srow & 3) ^ ((srow >> 2) & 3));
  const ushort* gA = Ybf  + (size_t)(m0 + srow) * 512 + schunk * 8;
  const ushort* gB = wObf + (size_t)(n0 + srow) * 512 + schunk * 8;

  floatx4 acc[4][4];
#pragma unroll
  for (int mi = 0; mi < 4; mi++)
#pragma unroll
    for (int ni = 0; ni < 4; ni++) acc[mi][ni] = (floatx4){0.f, 0.f, 0.f, 0.f};

#pragma unroll
  for (int t_ = 0; t_ < 2; t_++) {
    const ushort* ga = gA + t_ * 32;
    const ushort* gb = gB + t_ * 32;
    ushort* la = As + t_ * 4096 + tid * 8;
    ushort* lb = Bs + t_ * 4096 + tid * 8;
    gll16(ga, la); gll16(ga + 32768, la + 2048);
    gll16(gb, lb); gll16(gb + 32768, lb + 2048);
  }
  int cs = 0, ss = 2;

#pragma unroll 1
  for (int kt = 0; kt < 15; ++kt) GSTEP(512, "4", kt <= 13, kt);
  GSTEP(512, "0", false, 15);

#pragma unroll
  for (int mi = 0; mi < 4; mi++) {
    const int rm = m0 + wm + mi * 16 + lg * 4;
#pragma unroll
    for (int ni = 0; ni < 4; ni++) {
      const int cn = n0 + wn + ni * 16 + l15;
#pragma unroll
      for (int j = 0; j < 4; j++)
        out[(size_t)(rm + j) * 1024 + cn] = acc[mi][ni][j];
    }
  }
}

// ---------------- gate/mix ----------------
__global__ __launch_bounds__(256)
void gate_kernel(const float* __restrict__ Glin, const float* __restrict__ bG,
                 const float* __restrict__ Kp, const float* __restrict__ Vp,
                 float* __restrict__ gK, float* __restrict__ gV, float* __restrict__ Aout)
{
  const int nt = blockIdx.x * 4 + (threadIdx.x >> 6);
  const int lane = threadIdx.x & 63;
  const int n = nt >> 12;
  const int t = nt & 4095;

  float g[32];
  float gsum[4] = {0.f, 0.f, 0.f, 0.f};
#pragma unroll
  for (int f = 0; f < 32; f++) {
    float z = Glin[(size_t)nt * 32 + f] + bG[f];
    float s = 1.f / (1.f + __expf(-z));
    g[f] = s;
    gsum[f & 3] += s;
  }
  if (lane < 4) {
    float a = 1.f - fminf(gsum[lane], 1.f);
    Aout[(size_t)(n * 4 + lane) * 4096 + t] = a;
  }
  float gk[4] = {0.f, 0.f, 0.f, 0.f}, gv[4] = {0.f, 0.f, 0.f, 0.f};
#pragma unroll
  for (int h = 0; h < 8; h++) {
    float kv = Kp[(size_t)nt * 512 + h * 64 + lane];
    float vv = Vp[(size_t)nt * 512 + h * 64 + lane];
#pragma unroll
    for (int e = 0; e < 4; e++) {
      gk[e] = fmaf(g[h * 4 + e], kv, gk[e]);
      gv[e] = fmaf(g[h * 4 + e], vv, gv[e]);
    }
  }
#pragma unroll
  for (int e = 0; e < 4; e++) {
    size_t base = ((size_t)(n * 4 + e) * 4096 + t) * 64 + lane;
    gK[base] = gk[e];
    gV[base] = gv[e];
  }
}

// ---------------- chunked scan ----------------
__global__ __launch_bounds__(64)
void scan_kernel(float* __restrict__ gK, float* __restrict__ gV,
                 const float* __restrict__ Aarr,
                 const float* __restrict__ initK, const float* __restrict__ initV)
{
  __shared__ float sB[128 * 64];
  __shared__ float sA[128];
  const int b = blockIdx.x;
  const int half = b >> 8, sub = b & 255;
  float* gX = half ? gV : gK;
  const float* initX = half ? initV : initK;
  const int n = sub >> 7, r = sub & 127, e = r >> 5, l = r & 31;
  const int tbase = l * 128;
  const size_t base = ((size_t)(n * 4 + e) * 4096 + tbase) * 64;
  const int tid = threadIdx.x;

  const f4* src = (const f4*)&gX[base];
#pragma unroll
  for (int q = 0; q < 32; q++)
    *(f4*)&sB[(tid + q * 64) * 4] = src[tid + q * 64];
  sA[tid]      = Aarr[(size_t)(n * 4 + e) * 4096 + tbase + tid];
  sA[64 + tid] = Aarr[(size_t)(n * 4 + e) * 4096 + tbase + 64 + tid];
  __syncthreads();

  float state = initX[((size_t)e * 32 + l) * 64 + tid];
  float* dst = &gX[base];
  for (int c = 0; c < 128; c++) {
    state = fmaf(sA[c], state, sB[c * 64 + tid]);
    dst[c * 64 + tid] = state;
  }
}

// ---------------- 8-wave MFMA window attention ----------------
// Waves 0-3: experts {0,1}; waves 4-7: experts {2,3} (same query rows).
// Each group: QK -> masked softmax (local m,l) -> PV partial. Flash-merge via LDS.
__global__ __launch_bounds__(512, 1)
void attn_mfma8(const ushort* __restrict__ Qbf, const float* __restrict__ nK,
                const float* __restrict__ nV, const float* __restrict__ initK,
                const float* __restrict__ initV, ushort* __restrict__ Yout)
{
  __shared__ ushort Kw[4][4096];   // [e][u*64+d] bf16, byte ^ ((u&7)<<4)
  __shared__ ushort Vt[4][4096];   // [e][d*64+u] bf16, byte ^ ((d&7)<<4)
  __shared__ ushort Pl[8][4096];   // per-wave P; reused as f32 Y-exchange (64KB)
  __shared__ float sM[4][64];
  __shared__ float sL[4][64];

  const int blk = blockIdx.x;
  const int n = blk >> 7, c = blk & 127;
  const int t0 = c * 32;
  const int tid = threadIdx.x;
  const int lane = tid & 63;
  const int w = tid >> 6;          // 0..7
  const int w4 = w & 3;
  const int hv = w >> 2;           // expert-half
  const int l15 = lane & 15, lg = lane >> 4;

  // ---- Q A-fragments (pre-scaled bf16); rows shared by wave pairs ----
  short8 qf[4][2];
#pragma unroll
  for (int mi = 0; mi < 4; mi++) {
    int m = w4 * 64 + mi * 16 + l15;
    int t = t0 + (m & 31), h = m >> 5;
    const ushort* src = &Qbf[((size_t)(n * 4096 + t)) * 512 + h * 64];
#pragma unroll
    for (int kk = 0; kk < 2; kk++)
      qf[mi][kk] = *(const short8*)&src[kk * 32 + lg * 8];
  }

  // ---- stage K/V window: 4e x 64u x 64d bf16, swizzled; u==63 zeroed ----
#pragma unroll 4
  for (int it = 0; it < 8; it++) {
    int idx = it * 512 + tid;
    int e = idx >> 10, u = (idx >> 4) & 63, d = (idx & 15) * 4;
    int s = t0 - 31 + u;
    int scl = s < 4095 ? s : 4095;
    const float* pK = (s >= 0) ? &nK[(((size_t)(n * 4 + e)) * 4096 + scl) * 64 + d]
                               : &initK[((size_t)e * 32 + (s + 32)) * 64 + d];
    const float* pV = (s >= 0) ? &nV[(((size_t)(n * 4 + e)) * 4096 + scl) * 64 + d]
                               : &initV[((size_t)e * 32 + (s + 32)) * 64 + d];
    f4 kv = *(const f4*)pK;
    f4 vv = *(const f4*)pV;
    if (u == 63) { kv = make_float4(0.f,0.f,0.f,0.f); vv = make_float4(0.f,0.f,0.f,0.f); }
    uint2 kp; kp.x = pk2(kv.x, kv.y); kp.y = pk2(kv.z, kv.w);
    int ka = (u * 128 + d * 2) ^ ((u & 7) << 4);
    *(uint2*)((char*)&Kw[e][0] + ka) = kp;
    ushort vb[4] = { f2bf(vv.x), f2bf(vv.y), f2bf(vv.z), f2bf(vv.w) };
#pragma unroll
    for (int q = 0; q < 4; q++) {
      int dq = d + q;
      int va = (dq * 128 + u * 2) ^ ((dq & 7) << 4);
      *(ushort*)((char*)&Vt[e][0] + va) = vb[q];
    }
  }
  __syncthreads();

  floatx4 Yacc[4][4];
#pragma unroll
  for (int mi = 0; mi < 4; mi++)
#pragma unroll
    for (int nd = 0; nd < 4; nd++) Yacc[mi][nd] = (floatx4){0.f,0.f,0.f,0.f};
  float mrun[4][4], lrun[4][4];
#pragma unroll
  for (int mi = 0; mi < 4; mi++)
#pragma unroll
    for (int r = 0; r < 4; r++) { mrun[mi][r] = -1e30f; lrun[mi][r] = 0.f; }

  const floatx4 zf = (floatx4){0.f,0.f,0.f,0.f};
  char* pb = (char*)&Pl[w][0];

  {
    floatx4 S[2][4][4];
    // ---- QK^T for this group's 2 experts ----
#pragma unroll
    for (int ep = 0; ep < 2; ep++) {
      const int e = hv * 2 + ep;
#pragma unroll
      for (int ni = 0; ni < 4; ni++) {
        const int urow = ni * 16 + l15;
        const int sw = (urow & 7) << 4;
        short8 kf0 = *(const short8*)((const char*)&Kw[e][0] + ((urow * 128 + lg * 16) ^ sw));
        short8 kf1 = *(const short8*)((const char*)&Kw[e][0] + ((urow * 128 + 64 + lg * 16) ^ sw));
#pragma unroll
        for (int mi = 0; mi < 4; mi++) {
          floatx4 t_ = __builtin_amdgcn_mfma_f32_16x16x32_bf16(qf[mi][0], kf0, zf, 0, 0, 0);
          S[ep][mi][ni] = __builtin_amdgcn_mfma_f32_16x16x32_bf16(qf[mi][1], kf1, t_, 0, 0, 0);
        }
      }
    }
    // ---- mask + softmax (local to this half) ----
#pragma unroll
    for (int mi = 0; mi < 4; mi++)
#pragma unroll
      for (int r = 0; r < 4; r++) {
        const int iq = (mi & 1) * 16 + lg * 4 + r;
        float mx = mrun[mi][r];
#pragma unroll
        for (int ep = 0; ep < 2; ep++)
#pragma unroll
          for (int ni = 0; ni < 4; ni++) {
            const int u = ni * 16 + l15;
            float v = ((unsigned)(u - iq) < 32u) ? S[ep][mi][ni][r] : -1e30f;
            S[ep][mi][ni][r] = v;
            mx = fmaxf(mx, v);
          }
        mx = fmaxf(mx, __shfl_xor(mx, 1));
        mx = fmaxf(mx, __shfl_xor(mx, 2));
        mx = fmaxf(mx, __shfl_xor(mx, 4));
        mx = fmaxf(mx, __shfl_xor(mx, 8));
        mrun[mi][r] = mx;
        float sum = 0.f;
#pragma unroll
        for (int ep = 0; ep < 2; ep++)
#pragma unroll
          for (int ni = 0; ni < 4; ni++) {
            float p = __expf(S[ep][mi][ni][r] - mx);
            S[ep][mi][ni][r] = p;
            sum += p;
          }
        sum += __shfl_xor(sum, 1);
        sum += __shfl_xor(sum, 2);
        sum += __shfl_xor(sum, 4);
        sum += __shfl_xor(sum, 8);
        lrun[mi][r] = sum;
      }
    // ---- per expert: P -> LDS, PV MFMA ----
#pragma unroll
    for (int ep = 0; ep < 2; ep++) {
      const int e = hv * 2 + ep;
#pragma unroll
      for (int mi = 0; mi < 4; mi++)
#pragma unroll
        for (int r = 0; r < 4; r++) {
          const int m = mi * 16 + lg * 4 + r;
          const int base = m * 128, sw = (m & 7) << 4;
#pragma unroll
          for (int ni = 0; ni < 4; ni++) {
            const int u = ni * 16 + l15;
            *(ushort*)(pb + ((base + u * 2) ^ sw)) = f2bf(S[ep][mi][ni][r]);
          }
        }
      asm volatile("s_waitcnt lgkmcnt(0)" ::: "memory");
      __builtin_amdgcn_sched_barrier(0);
#pragma unroll
      for (int kk = 0; kk < 2; kk++) {
        short8 pa[4];
#pragma unroll
        for (int mi = 0; mi < 4; mi++) {
          const int m = mi * 16 + l15;
          pa[mi] = *(const short8*)(pb + ((m * 128 + kk * 64 + lg * 16) ^ ((m & 7) << 4)));
        }
#pragma unroll
        for (int nd = 0; nd < 4; nd++) {
          const int dr = nd * 16 + l15;
          short8 vf = *(const short8*)((const char*)&Vt[e][0] +
                        ((dr * 128 + kk * 64 + lg * 16) ^ ((dr & 7) << 4)));
#pragma unroll
          for (int mi = 0; mi < 4; mi++)
            Yacc[mi][nd] = __builtin_amdgcn_mfma_f32_16x16x32_bf16(pa[mi], vf, Yacc[mi][nd], 0, 0, 0);
        }
      }
    }
  }

  // ---- flash-merge the two halves ----
  __syncthreads();
  float* exch = (float*)&Pl[0][0];   // 16384 f32: wave pair w4 at [w4*4096, +4096)
  if (w >= 4) {
#pragma unroll
    for (int mi = 0; mi < 4; mi++)
#pragma unroll
      for (int r = 0; r < 4; r++) {
        const int m4 = mi * 16 + lg * 4 + r;
        if (l15 == 0) { sM[w4][m4] = mrun[mi][r]; sL[w4][m4] = lrun[mi][r]; }
#pragma unroll
        for (int nd = 0; nd < 4; nd++)
          exch[w4 * 4096 + m4 * 64 + nd * 16 + l15] = Yacc[mi][nd][r];
      }
  }
  __syncthreads();
  if (w < 4) {
#pragma unroll
    for (int mi = 0; mi < 4; mi++)
#pragma unroll
      for (int r = 0; r < 4; r++) {
        const int m4 = mi * 16 + lg * 4 + r;
        const float m1 = sM[w4][m4], l1 = sL[w4][m4];
        const float m0 = mrun[mi][r], l0 = lrun[mi][r];
        const float mm = fmaxf(m0, m1);
        const float a0 = __expf(m0 - mm), a1 = __expf(m1 - mm);
        const float inv = 1.f / (l0 * a0 + l1 * a1);
        const int m = w4 * 64 + m4;
        const int t = t0 + (m & 31), h = m >> 5;
        ushort* dst = &Yout[((size_t)(n * 4096 + t)) * 512 + h * 64];
#pragma unroll
        for (int nd = 0; nd < 4; nd++) {
          const float y1 = exch[w4 * 4096 + m4 * 64 + nd * 16 + l15];
          dst[nd * 16 + l15] = f2bf((Yacc[mi][nd][r] * a0 + y1 * a1) * inv);
        }
      }
  }
}

extern "C" void kernel_launch(void* const* d_in, const int* in_sizes, int n_in,
                              void* d_out, int out_size, void* d_ws, size_t ws_size,
                              hipStream_t stream) {
  const float* X     = (const float*)d_in[0];
  const float* wG    = (const float*)d_in[1];
  const float* bG    = (const float*)d_in[2];
  const float* wK    = (const float*)d_in[3];
  const float* wV    = (const float*)d_in[4];
  const float* wQ    = (const float*)d_in[5];
  const float* wO    = (const float*)d_in[6];
  const float* initK = (const float*)d_in[7];
  const float* initV = (const float*)d_in[8];
  float* out = (float*)d_out;

  float* ws = (float*)d_ws;
  ushort* Xbf  = (ushort*)(ws + 0);
  float*  gK   = ws + 0;
  float*  gV   = ws + 2097152;
  ushort* wAll = (ushort*)(ws + 4194304);     // 1664x1024 bf16
  ushort* wObf = (ushort*)(ws + 5111808);     // 1024x512 bf16
  float*  Glin = ws + 5373952;                // 8192x32 f32
  float*  Kp   = ws + 5636096;                // 8192x512 f32 -> later Ybf (bf16)
  ushort* Ybf  = (ushort*)Kp;
  float*  Vp   = ws + 9830400;                // 8192x512 f32
  ushort* Qbf  = (ushort*)(ws + 14024704);    // 8192x512 bf16 (pre-scaled 1/8)
  float*  Aarr = ws + 16121856;               // 2*4*4096

  prep_kernel<<<5760, 256, 0, stream>>>(X, wK, wV, wQ, wG, wO, Xbf, wAll, wObf);
  proj_gemm_128s<<<832, 256, 0, stream>>>(Xbf, wAll, Kp, Vp, Qbf, Glin);
  gate_kernel<<<2048, 256, 0, stream>>>(Glin, bG, Kp, Vp, gK, gV, Aarr);
  scan_kernel<<<512, 64, 0, stream>>>(gK, gV, Aarr, initK, initV);
  attn_mfma8<<<256, 512, 0, stream>>>(Qbf, gK, gV, initK, initV, Ybf);
  out_gemm_128s<<<512, 256, 0, stream>>>(Ybf, wObf, out);
}

// Round 10
// 209.916 us; speedup vs baseline: 1.1308x; 1.1308x over previous
//
#include <hip/hip_runtime.h>
#include <hip/hip_bf16.h>

// Caterpillar: N=2 T=4096 D=1024 H=8 E=4 L=32 DK=DV=64
// R9 (resubmit; prior round was GPUAcquisitionTimeout): proj = R4 2-barrier inner
// loop + R7 XCD single-pass grid + Qbf epilogue (16KB LDS, 4 blocks/CU);
// out = R4 exact; attn = R7 4-wave exact; prep = 3 separate kernels.

using f4 = float4;
typedef __attribute__((ext_vector_type(8))) short short8;   // 8 bf16
typedef __attribute__((ext_vector_type(4))) float floatx4;  // 4 fp32 acc

__device__ __forceinline__ ushort f2bf(float x) {
  unsigned u = __float_as_uint(x);
  u += 0x7fffu + ((u >> 16) & 1u);   // RNE
  return (ushort)(u >> 16);
}
__device__ __forceinline__ unsigned pk2(float lo, float hi) {
  return (unsigned)f2bf(lo) | ((unsigned)f2bf(hi) << 16);
}

__device__ __forceinline__ void gll16(const void* g, void* l) {
  __builtin_amdgcn_global_load_lds((const __attribute__((address_space(1))) void*)g,
                                   (__attribute__((address_space(3))) void*)l, 16, 0, 0);
}

// ---------------- conversions ----------------
__global__ __launch_bounds__(256)
void conv_f32_bf16(const float* __restrict__ src, ushort* __restrict__ dst, int n4) {
  for (int i = blockIdx.x * blockDim.x + threadIdx.x; i < n4; i += gridDim.x * blockDim.x) {
    f4 v = ((const f4*)src)[i];
    ushort4 o; o.x = f2bf(v.x); o.y = f2bf(v.y); o.z = f2bf(v.z); o.w = f2bf(v.w);
    ((ushort4*)dst)[i] = o;
  }
}

// wAll rows: [0,512)=wK, [512,1024)=wV, [1024,1536)=wQ, [1536,1568)=wG, [1568,1664)=0
__global__ __launch_bounds__(256)
void conv_weights(const float* __restrict__ wK, const float* __restrict__ wV,
                  const float* __restrict__ wQ, const float* __restrict__ wG,
                  ushort* __restrict__ wAll) {
  int i4 = blockIdx.x * 256 + threadIdx.x;     // 0..425983
  int idx = i4 * 4;
  int row = idx >> 10;
  f4 v = make_float4(0.f, 0.f, 0.f, 0.f);
  if (row < 512)       v = *(const f4*)&wK[idx];
  else if (row < 1024) v = *(const f4*)&wV[idx - 524288];
  else if (row < 1536) v = *(const f4*)&wQ[idx - 1048576];
  else if (row < 1568) v = *(const f4*)&wG[idx - 1572864];
  ushort4 o; o.x = f2bf(v.x); o.y = f2bf(v.y); o.z = f2bf(v.z); o.w = f2bf(v.w);
  *(ushort4*)&wAll[idx] = o;
}

__global__ __launch_bounds__(256)
void transpose_wO(const float* __restrict__ wO, ushort* __restrict__ wObf) {
  int i = blockIdx.x * 256 + threadIdx.x;
  int n = i >> 9, k = i & 511;
  wObf[i] = f2bf(wO[(size_t)k * 1024 + n]);
}

// ---------------- projection GEMM: R4 2-barrier loop + R7 grid/epilogue ----------------
// C[m,f] = sum_k Xbf[m,k]*wAll[f,k]; grid 832 = 8 XCD x (13 ct x 8 my).
__global__ __launch_bounds__(256, 4)
void proj_gemm_m97(const ushort* __restrict__ Xbf, const ushort* __restrict__ wAll,
                   float* __restrict__ Kp, float* __restrict__ Vp,
                   ushort* __restrict__ Qbf, float* __restrict__ Glin)
{
  __shared__ ushort As[4096];   // 128 rows x 32 k, k-contiguous
  __shared__ ushort Bs[4096];

  const int tid = threadIdx.x;
  const int bid = blockIdx.x;               // 0..831, XCD-chunked
  const int xcd = bid & 7, slot = bid >> 3; // slot 0..103
  const int ct = slot % 13;                 // col-tile 0..12
  const int my = xcd * 8 + slot / 13;       // 0..63
  const int m0 = my * 128, n0 = ct * 128;

  const int lane = tid & 63, w = tid >> 6;
  const int wm = (w >> 1) * 64, wn = (w & 1) * 64;
  const int l15 = lane & 15, lg = lane >> 4;

  const int srow = tid >> 2, scol = (tid & 3) * 8;
  const ushort* gA = Xbf  + (size_t)(m0 + srow) * 1024 + scol;
  const ushort* gB = wAll + (size_t)(n0 + srow) * 1024 + scol;
  ushort* lA0 = &As[tid * 8]; ushort* lA1 = &As[2048 + tid * 8];
  ushort* lB0 = &Bs[tid * 8]; ushort* lB1 = &Bs[2048 + tid * 8];

  floatx4 acc[4][4];
#pragma unroll
  for (int i = 0; i < 4; i++)
#pragma unroll
    for (int j = 0; j < 4; j++) acc[i][j] = (floatx4){0.f, 0.f, 0.f, 0.f};

  const short8* pA[4]; const short8* pB[4];
#pragma unroll
  for (int i = 0; i < 4; i++) {
    pA[i] = (const short8*)&As[(wm + i * 16 + l15) * 32 + lg * 8];
    pB[i] = (const short8*)&Bs[(wn + i * 16 + l15) * 32 + lg * 8];
  }

  for (int k0 = 0; k0 < 1024; k0 += 32) {
    gll16(gA + k0, lA0);
    gll16(gA + 65536 + k0, lA1);   // rows +64
    gll16(gB + k0, lB0);
    gll16(gB + 65536 + k0, lB1);
    __syncthreads();
    short8 a[4], b[4];
#pragma unroll
    for (int i = 0; i < 4; i++) { a[i] = *pA[i]; b[i] = *pB[i]; }
#pragma unroll
    for (int mi = 0; mi < 4; mi++)
#pragma unroll
      for (int ni = 0; ni < 4; ni++)
        acc[mi][ni] = __builtin_amdgcn_mfma_f32_16x16x32_bf16(a[mi], b[ni], acc[mi][ni], 0, 0, 0);
    __syncthreads();
  }

  // epilogue: split columns K/V/Q(bf16, x0.125)/G
#pragma unroll
  for (int mi = 0; mi < 4; mi++) {
    const int rm = m0 + wm + mi * 16 + lg * 4;
#pragma unroll
    for (int ni = 0; ni < 4; ni++) {
      const int Cg = n0 + wn + ni * 16 + l15;
#pragma unroll
      for (int j = 0; j < 4; j++) {
        const float v = acc[mi][ni][j];
        if (Cg < 512)        Kp [(size_t)(rm + j) * 512 + Cg] = v;
        else if (Cg < 1024)  Vp [(size_t)(rm + j) * 512 + Cg - 512] = v;
        else if (Cg < 1536)  Qbf[(size_t)(rm + j) * 512 + Cg - 1024] = f2bf(v * 0.125f);
        else if (Cg < 1568)  Glin[(size_t)(rm + j) * 32 + Cg - 1536] = v;
      }
    }
  }
}

// ---------------- output GEMM (R4 exact): out = Ybf(8192x512) @ wObf^T ----------------
__global__ __launch_bounds__(256, 4)
void out_gemm_mfma(const ushort* __restrict__ Ybf, const ushort* __restrict__ wObf,
                   float* __restrict__ out)
{
  __shared__ ushort As[4096];
  __shared__ ushort Bs[4096];
  const int tid = threadIdx.x;
  const int m0 = blockIdx.y * 128;
  const int n0 = blockIdx.x * 128;
  const int lane = tid & 63;
  const int wv = tid >> 6;
  const int wm = (wv >> 1) * 64, wn = (wv & 1) * 64;

  const int srow = tid >> 2, scol = (tid & 3) * 8;
  const ushort* gA = Ybf  + (size_t)(m0 + srow) * 512 + scol;
  const ushort* gB = wObf + (size_t)(n0 + srow) * 512 + scol;
  ushort* lA0 = &As[tid * 8]; ushort* lA1 = &As[2048 + tid * 8];
  ushort* lB0 = &Bs[tid * 8]; ushort* lB1 = &Bs[2048 + tid * 8];

  floatx4 acc[4][4];
#pragma unroll
  for (int i = 0; i < 4; i++)
#pragma unroll
    for (int j = 0; j < 4; j++) acc[i][j] = (floatx4){0.f, 0.f, 0.f, 0.f};

  const int fr = lane & 15;
  const int fk = (lane >> 4) * 8;
  const short8* pA[4]; const short8* pB[4];
#pragma unroll
  for (int i = 0; i < 4; i++) {
    pA[i] = (const short8*)&As[(wm + i * 16 + fr) * 32 + fk];
    pB[i] = (const short8*)&Bs[(wn + i * 16 + fr) * 32 + fk];
  }

  for (int k0 = 0; k0 < 512; k0 += 32) {
    gll16(gA + k0, lA0);
    gll16(gA + 32768 + k0, lA1);
    gll16(gB + k0, lB0);
    gll16(gB + 32768 + k0, lB1);
    __syncthreads();
    short8 a[4], b[4];
#pragma unroll
    for (int i = 0; i < 4; i++) { a[i] = *pA[i]; b[i] = *pB[i]; }
#pragma unroll
    for (int mi = 0; mi < 4; mi++)
#pragma unroll
      for (int ni = 0; ni < 4; ni++)
        acc[mi][ni] = __builtin_amdgcn_mfma_f32_16x16x32_bf16(a[mi], b[ni], acc[mi][ni], 0, 0, 0);
    __syncthreads();
  }

  const int fq = lane >> 4;
#pragma unroll
  for (int mi = 0; mi < 4; mi++) {
    int rm = m0 + wm + mi * 16 + fq * 4;
#pragma unroll
    for (int ni = 0; ni < 4; ni++) {
      int cn = n0 + wn + ni * 16 + fr;
#pragma unroll
      for (int j = 0; j < 4; j++)
        out[(size_t)(rm + j) * 1024 + cn] = acc[mi][ni][j];
    }
  }
}

// ---------------- gate/mix ----------------
__global__ __launch_bounds__(256)
void gate_kernel(const float* __restrict__ Glin, const float* __restrict__ bG,
                 const float* __restrict__ Kp, const float* __restrict__ Vp,
                 float* __restrict__ gK, float* __restrict__ gV, float* __restrict__ Aout)
{
  const int nt = blockIdx.x * 4 + (threadIdx.x >> 6);
  const int lane = threadIdx.x & 63;
  const int n = nt >> 12;
  const int t = nt & 4095;

  float g[32];
  float gsum[4] = {0.f, 0.f, 0.f, 0.f};
#pragma unroll
  for (int f = 0; f < 32; f++) {
    float z = Glin[(size_t)nt * 32 + f] + bG[f];
    float s = 1.f / (1.f + __expf(-z));
    g[f] = s;
    gsum[f & 3] += s;
  }
  if (lane < 4) {
    float a = 1.f - fminf(gsum[lane], 1.f);
    Aout[(size_t)(n * 4 + lane) * 4096 + t] = a;
  }
  float gk[4] = {0.f, 0.f, 0.f, 0.f}, gv[4] = {0.f, 0.f, 0.f, 0.f};
#pragma unroll
  for (int h = 0; h < 8; h++) {
    float kv = Kp[(size_t)nt * 512 + h * 64 + lane];
    float vv = Vp[(size_t)nt * 512 + h * 64 + lane];
#pragma unroll
    for (int e = 0; e < 4; e++) {
      gk[e] = fmaf(g[h * 4 + e], kv, gk[e]);
      gv[e] = fmaf(g[h * 4 + e], vv, gv[e]);
    }
  }
#pragma unroll
  for (int e = 0; e < 4; e++) {
    size_t base = ((size_t)(n * 4 + e) * 4096 + t) * 64 + lane;
    gK[base] = gk[e];
    gV[base] = gv[e];
  }
}

// ---------------- chunked scan ----------------
__global__ __launch_bounds__(64)
void scan_kernel(float* __restrict__ gK, float* __restrict__ gV,
                 const float* __restrict__ Aarr,
                 const float* __restrict__ initK, const float* __restrict__ initV)
{
  __shared__ float sB[128 * 64];
  __shared__ float sA[128];
  const int b = blockIdx.x;
  const int half = b >> 8, sub = b & 255;
  float* gX = half ? gV : gK;
  const float* initX = half ? initV : initK;
  const int n = sub >> 7, r = sub & 127, e = r >> 5, l = r & 31;
  const int tbase = l * 128;
  const size_t base = ((size_t)(n * 4 + e) * 4096 + tbase) * 64;
  const int tid = threadIdx.x;

  const f4* src = (const f4*)&gX[base];
#pragma unroll
  for (int q = 0; q < 32; q++)
    *(f4*)&sB[(tid + q * 64) * 4] = src[tid + q * 64];
  sA[tid]      = Aarr[(size_t)(n * 4 + e) * 4096 + tbase + tid];
  sA[64 + tid] = Aarr[(size_t)(n * 4 + e) * 4096 + tbase + 64 + tid];
  __syncthreads();

  float state = initX[((size_t)e * 32 + l) * 64 + tid];
  float* dst = &gX[base];
  for (int c = 0; c < 128; c++) {
    state = fmaf(sA[c], state, sB[c * 64 + tid]);
    dst[c * 64 + tid] = state;
  }
}

// ---------------- MFMA window attention (R7 exact, 4-wave) ----------------
__global__ __launch_bounds__(256, 1)
void attn_mfma(const ushort* __restrict__ Qbf, const float* __restrict__ nK,
               const float* __restrict__ nV, const float* __restrict__ initK,
               const float* __restrict__ initV, ushort* __restrict__ Yout)
{
  __shared__ ushort Kw[4][4096];   // [e][u*64+d] bf16, byte ^ ((u&7)<<4)
  __shared__ ushort Vt[4][4096];   // [e][d*64+u] bf16, byte ^ ((d&7)<<4)
  __shared__ ushort Pl[4][4096];   // per-wave P [m*64+u],  ^ ((m&7)<<4)

  const int blk = blockIdx.x;
  const int n = blk >> 7, c = blk & 127;
  const int t0 = c * 32;
  const int tid = threadIdx.x;
  const int lane = tid & 63;
  const int w = tid >> 6;
  const int l15 = lane & 15, lg = lane >> 4;

  short8 qf[4][2];
#pragma unroll
  for (int mi = 0; mi < 4; mi++) {
    int m = w * 64 + mi * 16 + l15;
    int t = t0 + (m & 31), h = m >> 5;
    const ushort* src = &Qbf[((size_t)(n * 4096 + t)) * 512 + h * 64];
#pragma unroll
    for (int kk = 0; kk < 2; kk++)
      qf[mi][kk] = *(const short8*)&src[kk * 32 + lg * 8];
  }

#pragma unroll 4
  for (int it = 0; it < 16; it++) {
    int idx = it * 256 + tid;
    int e = idx >> 10, u = (idx >> 4) & 63, d = (idx & 15) * 4;
    int s = t0 - 31 + u;
    int scl = s < 4095 ? s : 4095;
    const float* pK = (s >= 0) ? &nK[(((size_t)(n * 4 + e)) * 4096 + scl) * 64 + d]
                               : &initK[((size_t)e * 32 + (s + 32)) * 64 + d];
    const float* pV = (s >= 0) ? &nV[(((size_t)(n * 4 + e)) * 4096 + scl) * 64 + d]
                               : &initV[((size_t)e * 32 + (s + 32)) * 64 + d];
    f4 kv = *(const f4*)pK;
    f4 vv = *(const f4*)pV;
    if (u == 63) { kv = make_float4(0.f,0.f,0.f,0.f); vv = make_float4(0.f,0.f,0.f,0.f); }
    uint2 kp; kp.x = pk2(kv.x, kv.y); kp.y = pk2(kv.z, kv.w);
    int ka = (u * 128 + d * 2) ^ ((u & 7) << 4);
    *(uint2*)((char*)&Kw[e][0] + ka) = kp;
    ushort vb[4] = { f2bf(vv.x), f2bf(vv.y), f2bf(vv.z), f2bf(vv.w) };
#pragma unroll
    for (int q = 0; q < 4; q++) {
      int dq = d + q;
      int va = (dq * 128 + u * 2) ^ ((dq & 7) << 4);
      *(ushort*)((char*)&Vt[e][0] + va) = vb[q];
    }
  }
  __syncthreads();

  floatx4 Yacc[4][4];
#pragma unroll
  for (int mi = 0; mi < 4; mi++)
#pragma unroll
    for (int nd = 0; nd < 4; nd++) Yacc[mi][nd] = (floatx4){0.f,0.f,0.f,0.f};
  float mrun[4][4], lrun[4][4];
#pragma unroll
  for (int mi = 0; mi < 4; mi++)
#pragma unroll
    for (int r = 0; r < 4; r++) { mrun[mi][r] = -1e30f; lrun[mi][r] = 0.f; }

  const floatx4 zf = (floatx4){0.f,0.f,0.f,0.f};
  char* pb = (char*)&Pl[w][0];

#pragma unroll
  for (int half = 0; half < 2; half++) {
    floatx4 S[2][4][4];
#pragma unroll
    for (int ep = 0; ep < 2; ep++) {
      const int e = half * 2 + ep;
#pragma unroll
      for (int ni = 0; ni < 4; ni++) {
        const int urow = ni * 16 + l15;
        const int sw = (urow & 7) << 4;
        short8 kf0 = *(const short8*)((const char*)&Kw[e][0] + ((urow * 128 + lg * 16) ^ sw));
        short8 kf1 = *(const short8*)((const char*)&Kw[e][0] + ((urow * 128 + 64 + lg * 16) ^ sw));
#pragma unroll
        for (int mi = 0; mi < 4; mi++) {
          floatx4 t_ = __builtin_amdgcn_mfma_f32_16x16x32_bf16(qf[mi][0], kf0, zf, 0, 0, 0);
          S[ep][mi][ni] = __builtin_amdgcn_mfma_f32_16x16x32_bf16(qf[mi][1], kf1, t_, 0, 0, 0);
        }
      }
    }
#pragma unroll
    for (int mi = 0; mi < 4; mi++)
#pragma unroll
      for (int r = 0; r < 4; r++) {
        const int iq = (mi & 1) * 16 + lg * 4 + r;
        float mx = mrun[mi][r];
#pragma unroll
        for (int ep = 0; ep < 2; ep++)
#pragma unroll
          for (int ni = 0; ni < 4; ni++) {
            const int u = ni * 16 + l15;
            float v = ((unsigned)(u - iq) < 32u) ? S[ep][mi][ni][r] : -1e30f;
            S[ep][mi][ni][r] = v;
            mx = fmaxf(mx, v);
          }
        mx = fmaxf(mx, __shfl_xor(mx, 1));
        mx = fmaxf(mx, __shfl_xor(mx, 2));
        mx = fmaxf(mx, __shfl_xor(mx, 4));
        mx = fmaxf(mx, __shfl_xor(mx, 8));
        float sc = __expf(mrun[mi][r] - mx);
        mrun[mi][r] = mx;
        float sum = 0.f;
#pragma unroll
        for (int ep = 0; ep < 2; ep++)
#pragma unroll
          for (int ni = 0; ni < 4; ni++) {
            float p = __expf(S[ep][mi][ni][r] - mx);
            S[ep][mi][ni][r] = p;
            sum += p;
          }
        sum += __shfl_xor(sum, 1);
        sum += __shfl_xor(sum, 2);
        sum += __shfl_xor(sum, 4);
        sum += __shfl_xor(sum, 8);
        lrun[mi][r] = lrun[mi][r] * sc + sum;
#pragma unroll
        for (int nd = 0; nd < 4; nd++) Yacc[mi][nd][r] *= sc;
      }
#pragma unroll
    for (int ep = 0; ep < 2; ep++) {
      const int e = half * 2 + ep;
#pragma unroll
      for (int mi = 0; mi < 4; mi++)
#pragma unroll
        for (int r = 0; r < 4; r++) {
          const int m = mi * 16 + lg * 4 + r;
          const int base = m * 128, sw = (m & 7) << 4;
#pragma unroll
          for (int ni = 0; ni < 4; ni++) {
            const int u = ni * 16 + l15;
            *(ushort*)(pb + ((base + u * 2) ^ sw)) = f2bf(S[ep][mi][ni][r]);
          }
        }
      asm volatile("s_waitcnt lgkmcnt(0)" ::: "memory");
      __builtin_amdgcn_sched_barrier(0);
#pragma unroll
      for (int kk = 0; kk < 2; kk++) {
        short8 pa[4];
#pragma unroll
        for (int mi = 0; mi < 4; mi++) {
          const int m = mi * 16 + l15;
          pa[mi] = *(const short8*)(pb + ((m * 128 + kk * 64 + lg * 16) ^ ((m & 7) << 4)));
        }
#pragma unroll
        for (int nd = 0; nd < 4; nd++) {
          const int dr = nd * 16 + l15;
          short8 vf = *(const short8*)((const char*)&Vt[e][0] +
                        ((dr * 128 + kk * 64 + lg * 16) ^ ((dr & 7) << 4)));
#pragma unroll
          for (int mi = 0; mi < 4; mi++)
            Yacc[mi][nd] = __builtin_amdgcn_mfma_f32_16x16x32_bf16(pa[mi], vf, Yacc[mi][nd], 0, 0, 0);
        }
      }
    }
  }

#pragma unroll
  for (int mi = 0; mi < 4; mi++)
#pragma unroll
    for (int r = 0; r < 4; r++) {
      const float inv = 1.f / lrun[mi][r];
      const int m = w * 64 + mi * 16 + lg * 4 + r;
      const int t = t0 + (m & 31), h = m >> 5;
      ushort* dst = &Yout[((size_t)(n * 4096 + t)) * 512 + h * 64];
#pragma unroll
      for (int nd = 0; nd < 4; nd++)
        dst[nd * 16 + l15] = f2bf(Yacc[mi][nd][r] * inv);
    }
}

extern "C" void kernel_launch(void* const* d_in, const int* in_sizes, int n_in,
                              void* d_out, int out_size, void* d_ws, size_t ws_size,
                              hipStream_t stream) {
  const float* X     = (const float*)d_in[0];
  const float* wG    = (const float*)d_in[1];
  const float* bG    = (const float*)d_in[2];
  const float* wK    = (const float*)d_in[3];
  const float* wV    = (const float*)d_in[4];
  const float* wQ    = (const float*)d_in[5];
  const float* wO    = (const float*)d_in[6];
  const float* initK = (const float*)d_in[7];
  const float* initV = (const float*)d_in[8];
  float* out = (float*)d_out;

  float* ws = (float*)d_ws;
  ushort* Xbf  = (ushort*)(ws + 0);
  float*  gK   = ws + 0;
  float*  gV   = ws + 2097152;
  ushort* wAll = (ushort*)(ws + 4194304);     // 1664x1024 bf16
  ushort* wObf = (ushort*)(ws + 5111808);     // 1024x512 bf16
  float*  Glin = ws + 5373952;                // 8192x32 f32
  float*  Kp   = ws + 5636096;                // 8192x512 f32 -> later Ybf (bf16)
  ushort* Ybf  = (ushort*)Kp;
  float*  Vp   = ws + 9830400;                // 8192x512 f32
  ushort* Qbf  = (ushort*)(ws + 14024704);    // 8192x512 bf16 (pre-scaled 1/8)
  float*  Aarr = ws + 16121856;               // 2*4*4096

  conv_f32_bf16<<<2048, 256, 0, stream>>>(X, Xbf, 2097152);
  conv_weights<<<1664, 256, 0, stream>>>(wK, wV, wQ, wG, wAll);
  transpose_wO<<<2048, 256, 0, stream>>>(wO, wObf);
  proj_gemm_m97<<<832, 256, 0, stream>>>(Xbf, wAll, Kp, Vp, Qbf, Glin);
  gate_kernel<<<2048, 256, 0, stream>>>(Glin, bG, Kp, Vp, gK, gV, Aarr);
  scan_kernel<<<512, 64, 0, stream>>>(gK, gV, Aarr, initK, initV);
  attn_mfma<<<256, 256, 0, stream>>>(Qbf, gK, gV, initK, initV, Ybf);
  out_gemm_mfma<<<dim3(8, 64), 256, 0, stream>>>(Ybf, wObf, out);
}